// Round 1
// baseline (112.877 us; speedup 1.0000x reference)
//
#include <hip/hip_runtime.h>

// CapsuleConv2d fused kernel (fp32, vector ALU).
// N=4, C=64 (G=8 x IN_LEN=8), H=W=32, O=8, L=16, F=G*9=72, 3x3 pad1 stride1.
// Wave = one (n,o) and 2 adjacent pixels; lane = (l = lane&15, fq = lane>>4).
// Each lane holds priors P[f = fq*18 + j][2 pix] and routing coeffs in regs.
// Weight LDS layout f*152 + l*9 + p  -> bank = (16*fq + 9*l + p)%32: exact 2-way (free).
// x window LDS channel-contiguous   -> float4 loads, 16-lane broadcast, 2-way across fq.

__device__ __forceinline__ float dpp_sum16(float v) {
  // full butterfly sum over the 16-lane row; result valid in all 16 lanes
  v += __int_as_float(__builtin_amdgcn_update_dpp(0, __float_as_int(v), 0xB1, 0xF, 0xF, true));  // quad_perm xor1
  v += __int_as_float(__builtin_amdgcn_update_dpp(0, __float_as_int(v), 0x4E, 0xF, 0xF, true));  // quad_perm xor2
  v += __int_as_float(__builtin_amdgcn_update_dpp(0, __float_as_int(v), 0x124, 0xF, 0xF, true)); // row_ror:4
  v += __int_as_float(__builtin_amdgcn_update_dpp(0, __float_as_int(v), 0x128, 0xF, 0xF, true)); // row_ror:8
  return v;
}

__global__ __launch_bounds__(256, 3)
void capsule_conv_kernel(const float* __restrict__ xsrc,
                         const float* __restrict__ wsrc,
                         float* __restrict__ out) {
  const int b  = blockIdx.x;
  const int wq = b & 3;          // 4 col-quads of 8 pixels
  const int h  = (b >> 2) & 31;
  const int o  = (b >> 7) & 7;
  const int n  = b >> 10;
  const int w0 = wq * 8;

  const int tid  = threadIdx.x;
  const int lane = tid & 63;
  const int wv   = tid >> 6;     // wave id 0..3 -> pixel pair
  const int l    = lane & 15;
  const int fq   = lane >> 4;

  __shared__ float wlds[72 * 152];   // 43776 B
  __shared__ float xlds[3 * 10 * 68]; // 8160 B (stride 68 keeps float4 alignment)

  // ---- stage weight slice for this o (9216 floats, coalesced) ----
  const float* wsl = wsrc + o * 9216;
  for (int i = tid; i < 9216; i += 256) {
    int f = i >> 7, r = i & 127, ll = r >> 3, p = r & 7;
    wlds[f * 152 + ll * 9 + p] = wsl[i];
  }
  // ---- stage x window: rows h-1..h+1, cols w0-1..w0+8, 64 channels ----
  for (int i = tid; i < 1920; i += 256) {
    int cc = i / 30, r = i % 30, kh = r / 10, col = r % 10;
    int hh = h - 1 + kh, ww = w0 - 1 + col;
    float v = 0.f;
    if ((unsigned)hh < 32u && (unsigned)ww < 32u)
      v = xsrc[((n * 64 + cc) * 32 + hh) * 32 + ww];
    xlds[(kh * 10 + col) * 68 + cc] = v;
  }
  __syncthreads();

  // ---- priors: P[j][pix] = sum_p w[o, f, l, p] * x[n, g*8+p, h+kh-1, w+kw-1] ----
  float P0[18], P1[18];
  const float* wbase = &wlds[fq * (18 * 152) + l * 9];
  const int colbase = wv * 2;  // pixel0 = w0 + wv*2; window col = (pix - w0) + kw
  #pragma unroll
  for (int j = 0; j < 18; ++j) {
    const int g  = 2 * fq + (j >= 9 ? 1 : 0); // f = fq*18+j; g = f/9
    const int s  = j % 9;                     // f%9 == j%9
    const int kh = s / 3, kw = s % 3;
    const float* wp = wbase + j * 152;
    const float w0_ = wp[0], w1_ = wp[1], w2_ = wp[2], w3_ = wp[3];
    const float w4_ = wp[4], w5_ = wp[5], w6_ = wp[6], w7_ = wp[7];
    const float* xpA = &xlds[(kh * 10 + colbase + kw) * 68 + g * 8];
    const float4 a0 = *reinterpret_cast<const float4*>(xpA);
    const float4 a1 = *reinterpret_cast<const float4*>(xpA + 4);
    const float4 b0 = *reinterpret_cast<const float4*>(xpA + 68);
    const float4 b1 = *reinterpret_cast<const float4*>(xpA + 72);
    P0[j] = w0_ * a0.x + w1_ * a0.y + w2_ * a0.z + w3_ * a0.w
          + w4_ * a1.x + w5_ * a1.y + w6_ * a1.z + w7_ * a1.w;
    P1[j] = w0_ * b0.x + w1_ * b0.y + w2_ * b0.z + w3_ * b0.w
          + w4_ * b1.x + w5_ * b1.y + w6_ * b1.z + w7_ * b1.w;
  }

  // ---- dynamic routing, 3 iterations, all in registers/cross-lane ----
  float c0[18], c1[18];
  #pragma unroll
  for (int j = 0; j < 18; ++j) { c0[j] = 1.f; c1[j] = 1.f; }

  float out0 = 0.f, out1 = 0.f;
  #pragma unroll
  for (int it = 0; it < 3; ++it) {
    float sp0 = 0.f, sp1 = 0.f;
    #pragma unroll
    for (int j = 0; j < 18; ++j) { sp0 += c0[j] * P0[j]; sp1 += c1[j] * P1[j]; }
    // sum across the 4 fq rows (72 f total), then mean over G=8
    sp0 += __shfl_xor(sp0, 16); sp0 += __shfl_xor(sp0, 32);
    sp1 += __shfl_xor(sp1, 16); sp1 += __shfl_xor(sp1, 32);
    const float s0 = sp0 * 0.125f, s1 = sp1 * 0.125f;
    // squash: out = s * sqrt(sq)/(1+sq), sq = sum_l s^2 (16-lane row reduce)
    const float q0 = dpp_sum16(s0 * s0);
    const float q1 = dpp_sum16(s1 * s1);
    const float k0 = sqrtf(q0) / (1.f + q0);
    const float k1 = sqrtf(q1) / (1.f + q1);
    out0 = s0 * k0; out1 = s1 * k1;
    if (it < 2) {
      #pragma unroll
      for (int j = 0; j < 18; ++j) {
        const float d0 = dpp_sum16(P0[j] * out0); // delta[f] = sum_l P[f,l]*out[l]
        const float d1 = dpp_sum16(P1[j] * out1);
        c0[j] += __expf(d0);
        c1[j] += __expf(d1);
      }
    }
  }

  // ---- write out[n][o*16+l][h][w] ----
  if (fq == 0) {
    const int wp0 = w0 + wv * 2;
    float* op = out + (((n * 8 + o) * 16 + l) * 32 + h) * 32;
    op[wp0]     = out0;
    op[wp0 + 1] = out1;
  }
}

extern "C" void kernel_launch(void* const* d_in, const int* in_sizes, int n_in,
                              void* d_out, int out_size, void* d_ws, size_t ws_size,
                              hipStream_t stream) {
  const float* x = (const float*)d_in[0];
  const float* w = (const float*)d_in[1];
  float* outp    = (float*)d_out;
  capsule_conv_kernel<<<dim3(4096), dim3(256), 0, stream>>>(x, w, outp);
}

// Round 2
// 82.088 us; speedup vs baseline: 1.3751x; 1.3751x over previous
//
#include <hip/hip_runtime.h>
#include <hip/hip_bf16.h>

// CapsuleConv2d fused, MFMA edition.
// N=4, C=64 (G=8 x IN_LEN=8), H=W=32, O=8, L=16, F=72 (G x 3x3), pad1 stride1.
//
// prep_w: w[o][f][l][p] fp32 -> wT records of 16 ushorts: [hi bf16 x8 | lo bf16 x8]
//         record index ((o*72+f)*16+l). A-fragment friendly (lane m reads 16B).
// prep_x: x[n][c][h][w] fp32 -> xT per pixel: 128 ushorts [hi c0..63 | lo c0..63].
// main:   block = (n,o,h,wtile16), 4 waves = 4 f-quadrants (18 f each).
//         Priors: one mfma_f32_16x16x32_bf16 per f: m=l, n=pix, K-octets =
//         (w_hi*x_hi)(p0..7) | (w_hi*x_lo) | (w_lo*x_hi) | zero  -> fp32-accurate.
//         D-layout: col=lane&15=pix, row=(lane>>4)*4+reg=l  [m89-verified].
//         A-layout: A[m=lane&15][k=(lane>>4)*8+j]; B[k=(lane>>4)*8+j][n=lane&15].
//         Routing in D-layout: s-partials in regs, cross-wave f-sum via LDS,
//         lq-reductions via 2x shfl_xor, exp only 4x redundant.

typedef short bf16x8 __attribute__((ext_vector_type(8)));
typedef float f32x4 __attribute__((ext_vector_type(4)));

__global__ void prep_w(const float* __restrict__ w, ushort* __restrict__ wT) {
  const int t = blockIdx.x * 256 + threadIdx.x;  // (o*72+f)*16+l, 9216 total
  if (t >= 9216) return;
  const float* src = w + t * 8;
  uint hi[4], lo[4];
  #pragma unroll
  for (int p2 = 0; p2 < 4; ++p2) {
    float v0 = src[p2 * 2], v1 = src[p2 * 2 + 1];
    __hip_bfloat16 h0 = __float2bfloat16(v0);
    __hip_bfloat16 h1 = __float2bfloat16(v1);
    __hip_bfloat16 l0 = __float2bfloat16(v0 - __bfloat162float(h0));
    __hip_bfloat16 l1 = __float2bfloat16(v1 - __bfloat162float(h1));
    hi[p2] = (uint)(*(ushort*)&h0) | ((uint)(*(ushort*)&h1) << 16);
    lo[p2] = (uint)(*(ushort*)&l0) | ((uint)(*(ushort*)&l1) << 16);
  }
  uint* dst = (uint*)(wT + t * 16);
  *(uint4*)dst       = make_uint4(hi[0], hi[1], hi[2], hi[3]);
  *(uint4*)(dst + 4) = make_uint4(lo[0], lo[1], lo[2], lo[3]);
}

__global__ void prep_x(const float* __restrict__ x, ushort* __restrict__ xT) {
  const int t = blockIdx.x * 256 + threadIdx.x;  // 32768: pix = t>>3, ch-octet = t&7
  const int pix = t >> 3, oct = t & 7;
  const int n = pix >> 10, hw = pix & 1023;
  const float* src = x + n * 65536 + oct * 8 * 1024 + hw;
  ushort* dst = xT + pix * 128 + oct * 8;
  #pragma unroll
  for (int k = 0; k < 8; ++k) {
    float v = src[k * 1024];
    __hip_bfloat16 h = __float2bfloat16(v);
    __hip_bfloat16 l = __float2bfloat16(v - __bfloat162float(h));
    dst[k]      = *(ushort*)&h;
    dst[64 + k] = *(ushort*)&l;
  }
}

__global__ __launch_bounds__(256, 4)
void caps_main(const ushort* __restrict__ wT, const ushort* __restrict__ xT,
               float* __restrict__ out) {
  const int b  = blockIdx.x;
  const int wt = b & 1, h = (b >> 1) & 31, o = (b >> 6) & 7, n = b >> 9;
  const int w0 = wt * 16;
  const int tid = threadIdx.x, lane = tid & 63, fq = tid >> 6;
  const int pix = lane & 15, q = lane >> 4;

  // x window: 3 rows x 18 cols, per col 64 words ([hi 32w | lo 32w]), stride 68 words
  __shared__ uint  xs[54 * 68];        // 14688 B
  __shared__ float sbuf[4 * 16 * 16];  // 16384 B cross-wave s exchange

  // ---- stage x window (pure uint4 copies; zero-fill pads) ----
  for (int i = tid; i < 54 * 16; i += 256) {
    const int r = i >> 4, seg = i & 15;
    const int kh = r / 18, c = r % 18;
    const int hh = h + kh - 1, ww = w0 + c - 1;
    uint4 v = make_uint4(0u, 0u, 0u, 0u);
    if ((unsigned)hh < 32u && (unsigned)ww < 32u) {
      const uint* g = (const uint*)xT + (n * 1024 + hh * 32 + ww) * 64 + seg * 4;
      v = *(const uint4*)g;
    }
    *(uint4*)&xs[r * 68 + seg * 4] = v;
  }
  __syncthreads();

  // ---- priors: 18 MFMAs, one per f = fq*18 + j ----
  f32x4 P[18];
  const f32x4 zacc = {0.f, 0.f, 0.f, 0.f};
  // A: lane m=pix reads 16B of w-record; octets q0,q1 -> hi, q2 -> lo, q3 -> 0
  const ushort* wA = wT + ((o * 72 + fq * 18) * 16 + pix) * 16 + ((q == 2) ? 8 : 0);
  const bool aload = (q < 3);
  // B: lane n=pix reads 16B of x col; octets q0,q2 -> hi, q1 -> lo, q3 -> (A=0 kills)
  const int xw_lane = pix * 68 + ((q == 1) ? 32 : 0);
  #pragma unroll
  for (int j = 0; j < 18; ++j) {
    const int g = fq * 2 + (j >= 9 ? 1 : 0);
    const int s = j % 9, kh = s / 3, kw = s % 3;
    bf16x8 a = {0, 0, 0, 0, 0, 0, 0, 0};
    if (aload) a = *(const bf16x8*)(wA + j * 256);
    const bf16x8 bv = *(const bf16x8*)&xs[(kh * 18 + kw) * 68 + g * 4 + xw_lane];
    P[j] = __builtin_amdgcn_mfma_f32_16x16x32_bf16(a, bv, zacc, 0, 0, 0);
  }

  // ---- routing: lane owns (pix, l = q*4 + reg), 18 f x 4 l priors in regs ----
  float c[18];
  #pragma unroll
  for (int j = 0; j < 18; ++j) c[j] = 1.f;

  const int sidx = pix * 16 + (q << 2);  // [pix][l] within a wave's 256-float tile
  #pragma unroll
  for (int it = 0; it < 3; ++it) {
    f32x4 sp = {0.f, 0.f, 0.f, 0.f};
    #pragma unroll
    for (int j = 0; j < 18; ++j) {
      sp.x += c[j] * P[j].x; sp.y += c[j] * P[j].y;
      sp.z += c[j] * P[j].z; sp.w += c[j] * P[j].w;
    }
    if (it) __syncthreads();           // protect sbuf from previous iteration's reads
    *(f32x4*)&sbuf[fq * 256 + sidx] = sp;
    __syncthreads();
    f32x4 S0 = *(const f32x4*)&sbuf[0 * 256 + sidx];
    f32x4 S1 = *(const f32x4*)&sbuf[1 * 256 + sidx];
    f32x4 S2 = *(const f32x4*)&sbuf[2 * 256 + sidx];
    f32x4 S3 = *(const f32x4*)&sbuf[3 * 256 + sidx];
    f32x4 sv;
    sv.x = (S0.x + S1.x + S2.x + S3.x) * 0.125f;
    sv.y = (S0.y + S1.y + S2.y + S3.y) * 0.125f;
    sv.z = (S0.z + S1.z + S2.z + S3.z) * 0.125f;
    sv.w = (S0.w + S1.w + S2.w + S3.w) * 0.125f;
    // squash: qq = sum_l s^2 (4 regs + reduce over lq lanes at stride 16)
    float qq = sv.x * sv.x + sv.y * sv.y + sv.z * sv.z + sv.w * sv.w;
    qq += __shfl_xor(qq, 16);
    qq += __shfl_xor(qq, 32);
    const float k = sqrtf(qq) / (1.f + qq);
    f32x4 ov;
    ov.x = sv.x * k; ov.y = sv.y * k; ov.z = sv.z * k; ov.w = sv.w * k;
    if (it < 2) {
      #pragma unroll
      for (int j = 0; j < 18; ++j) {
        float d = P[j].x * ov.x + P[j].y * ov.y + P[j].z * ov.z + P[j].w * ov.w;
        d += __shfl_xor(d, 16);
        d += __shfl_xor(d, 32);
        c[j] += __expf(d);
      }
    } else if (fq == 0) {
      // out[n][o*16 + l][h][w0+pix], l = q*4 + reg
      float* op = out + ((n * 8 + o) * 16 + (q << 2)) * 1024 + h * 32 + w0 + pix;
      op[0]    = ov.x;
      op[1024] = ov.y;
      op[2048] = ov.z;
      op[3072] = ov.w;
    }
  }
}

extern "C" void kernel_launch(void* const* d_in, const int* in_sizes, int n_in,
                              void* d_out, int out_size, void* d_ws, size_t ws_size,
                              hipStream_t stream) {
  const float* x = (const float*)d_in[0];
  const float* w = (const float*)d_in[1];
  float* outp    = (float*)d_out;
  ushort* wT = (ushort*)d_ws;                  // 9216 * 16 ushorts = 294912 B
  ushort* xT = (ushort*)((char*)d_ws + 294912); // 4096 * 128 ushorts = 1048576 B
  prep_w<<<dim3(36), dim3(256), 0, stream>>>(w, wT);
  prep_x<<<dim3(128), dim3(256), 0, stream>>>(x, xT);
  caps_main<<<dim3(2048), dim3(256), 0, stream>>>(wT, xT, outp);
}

// Round 3
// 78.157 us; speedup vs baseline: 1.4442x; 1.0503x over previous
//
#include <hip/hip_runtime.h>
#include <hip/hip_bf16.h>

// CapsuleConv2d fused, MFMA edition v2.
// N=4, C=64 (G=8 x IN_LEN=8), H=W=32, O=8, L=16, F=72 (G x 3x3), pad1 stride1.
//
// prep (1 kernel, 2 block ranges):
//   b<32  : x[n][c][h][w] fp32 -> xT per pixel: 64 uints [hi c0..63 | lo c0..63]
//           (bf16 split), via LDS transpose; coalesced reads AND writes.
//   b>=32 : w[o][f][l][p] fp32 -> wT records of 16 ushorts [hi p0..7 | lo p0..7].
// caps_main: block = (n,o,h,wtile16), 4 waves = 4 f-quadrants (18 f each).
//   Priors: one mfma_f32_16x16x32_bf16 per f; K-octets give the EXACT product:
//     q0: w_hi*x_hi, q1: w_hi*x_lo, q2: w_lo*x_hi, q3: w_lo*x_lo.
//   D-layout: col=lane&15=pix, row=(lane>>4)*4+reg=l  [m89-verified].
//   Routing in D-layout; cross-wave f-sum via double-buffered LDS (1 barrier/iter).
//   __launch_bounds__(256,3): VGPR cap 168 -> no spills (live state ~120 regs).

typedef short bf16x8 __attribute__((ext_vector_type(8)));
typedef float f32x4 __attribute__((ext_vector_type(4)));

__device__ __forceinline__ uint pack_split(float v) {
  __hip_bfloat16 hb = __float2bfloat16(v);
  float hf = __bfloat162float(hb);
  __hip_bfloat16 lb = __float2bfloat16(v - hf);
  return (uint)(*(ushort*)&hb) | ((uint)(*(ushort*)&lb) << 16);
}

__global__ __launch_bounds__(256)
void prep(const float* __restrict__ x, const float* __restrict__ w,
          ushort* __restrict__ wT, ushort* __restrict__ xT) {
  const int b = blockIdx.x;
  if (b < 32) {
    // ---- x part: n = b>>3, 4 h-rows starting h0 ----
    __shared__ uint lds[128 * 65];  // [pix 0..127][c 0..63], hi|lo packed
    const int n = b >> 3, h0 = (b & 7) * 4;
    const float* src = x + n * 65536 + h0 * 32;
    for (int i = threadIdx.x; i < 8192; i += 256) {
      const int c = i >> 7, p = i & 127;           // coalesced 128-float runs
      lds[p * 65 + c] = pack_split(src[c * 1024 + p]);
    }
    __syncthreads();
    uint* dst = (uint*)xT + (n * 1024 + h0 * 32) * 64;
    for (int i = threadIdx.x; i < 2048; i += 256) {
      const int pix = i >> 4, seg = i & 15;        // seg 0..7 -> hi, 8..15 -> lo
      const uint* row = &lds[pix * 65 + (seg & 7) * 8];
      uint4 v;
      if (seg < 8) {
        v.x = (row[0] & 0xffffu) | (row[1] << 16);
        v.y = (row[2] & 0xffffu) | (row[3] << 16);
        v.z = (row[4] & 0xffffu) | (row[5] << 16);
        v.w = (row[6] & 0xffffu) | (row[7] << 16);
      } else {
        v.x = (row[0] >> 16) | (row[1] & 0xffff0000u);
        v.y = (row[2] >> 16) | (row[3] & 0xffff0000u);
        v.z = (row[4] >> 16) | (row[5] & 0xffff0000u);
        v.w = (row[6] >> 16) | (row[7] & 0xffff0000u);
      }
      *(uint4*)(dst + pix * 64 + seg * 4) = v;     // fully coalesced 16B stores
    }
  } else {
    // ---- w part: t = record index (o*72+f)*16+l, 9216 total ----
    const int t = (b - 32) * 256 + threadIdx.x;
    if (t >= 9216) return;
    const float* src = w + t * 8;
    uint hi[4], lo[4];
    #pragma unroll
    for (int p2 = 0; p2 < 4; ++p2) {
      uint a = pack_split(src[p2 * 2]);
      uint c = pack_split(src[p2 * 2 + 1]);
      hi[p2] = (a & 0xffffu) | (c << 16);
      lo[p2] = (a >> 16) | (c & 0xffff0000u);
    }
    uint* dstp = (uint*)(wT + t * 16);
    *(uint4*)dstp       = make_uint4(hi[0], hi[1], hi[2], hi[3]);
    *(uint4*)(dstp + 4) = make_uint4(lo[0], lo[1], lo[2], lo[3]);
  }
}

__global__ __launch_bounds__(256, 3)
void caps_main(const ushort* __restrict__ wT, const ushort* __restrict__ xT,
               float* __restrict__ out) {
  const int b  = blockIdx.x;
  const int wt = b & 1, h = (b >> 1) & 31, o = (b >> 6) & 7, n = b >> 9;
  const int w0 = wt * 16;
  const int tid = threadIdx.x, lane = tid & 63, fq = tid >> 6;
  const int pix = lane & 15, q = lane >> 4;

  // x window: 3 rows x 18 cols, per col 64 uints ([hi 32 | lo 32]), stride 68
  __shared__ uint  xs[54 * 68];          // 14688 B
  __shared__ float sbuf[2][4 * 256];     // 8192 B, double-buffered s exchange

  // ---- stage x window (uint4 copies; zero-fill pads) ----
  for (int i = tid; i < 54 * 16; i += 256) {
    const int r = i >> 4, seg = i & 15;
    const int kh = r / 18, c = r % 18;
    const int hh = h + kh - 1, ww = w0 + c - 1;
    uint4 v = make_uint4(0u, 0u, 0u, 0u);
    if ((unsigned)hh < 32u && (unsigned)ww < 32u) {
      const uint* g = (const uint*)xT + (n * 1024 + hh * 32 + ww) * 64 + seg * 4;
      v = *(const uint4*)g;
    }
    *(uint4*)&xs[r * 68 + seg * 4] = v;
  }
  __syncthreads();

  // ---- priors: 18 MFMAs, one per f = fq*18 + j; exact bf16-split product ----
  f32x4 P[18];
  const f32x4 zacc = {0.f, 0.f, 0.f, 0.f};
  // A (lane m = l = pix index of A row? no: m-lane = lane&15 holds row m): here
  // m = l; record for (o, f, l=pix-lane) read at hi (q<2) or lo (q>=2) half.
  const ushort* wA = wT + ((o * 72 + fq * 18) * 16 + pix) * 16 + ((q >= 2) ? 8 : 0);
  // B: k-octet q -> hi (q even) / lo (q odd) halves of the x column.
  const int xw_lane = pix * 68 + ((q & 1) ? 32 : 0);
  #pragma unroll
  for (int j = 0; j < 18; ++j) {
    const int g = fq * 2 + (j >= 9 ? 1 : 0);
    const int s = j % 9, kh = s / 3, kw = s % 3;
    const bf16x8 a  = *(const bf16x8*)(wA + j * 256);
    const bf16x8 bv = *(const bf16x8*)&xs[(kh * 18 + kw) * 68 + g * 4 + xw_lane];
    P[j] = __builtin_amdgcn_mfma_f32_16x16x32_bf16(a, bv, zacc, 0, 0, 0);
  }

  // ---- routing: lane owns (pix, l = q*4 + reg), 18 f x 4 l priors in regs ----
  float c[18];
  #pragma unroll
  for (int j = 0; j < 18; ++j) c[j] = 1.f;

  const int sidx = pix * 16 + (q << 2);  // [pix][l] within a wave's 256-float tile
  #pragma unroll
  for (int it = 0; it < 3; ++it) {
    f32x4 sp = {0.f, 0.f, 0.f, 0.f};
    #pragma unroll
    for (int j = 0; j < 18; ++j) {
      sp.x += c[j] * P[j].x; sp.y += c[j] * P[j].y;
      sp.z += c[j] * P[j].z; sp.w += c[j] * P[j].w;
    }
    float* sb = sbuf[it & 1];
    *(f32x4*)&sb[fq * 256 + sidx] = sp;
    __syncthreads();
    f32x4 sv = *(const f32x4*)&sb[sidx];
    #pragma unroll
    for (int k4 = 1; k4 < 4; ++k4) {
      f32x4 t = *(const f32x4*)&sb[k4 * 256 + sidx];
      sv.x += t.x; sv.y += t.y; sv.z += t.z; sv.w += t.w;
    }
    sv.x *= 0.125f; sv.y *= 0.125f; sv.z *= 0.125f; sv.w *= 0.125f;
    // squash: qq = sum_l s^2  (4 regs + reduce over the 4 lq lanes)
    float qq = sv.x * sv.x + sv.y * sv.y + sv.z * sv.z + sv.w * sv.w;
    qq += __shfl_xor(qq, 16);
    qq += __shfl_xor(qq, 32);
    const float k = sqrtf(qq) / (1.f + qq);
    f32x4 ov;
    ov.x = sv.x * k; ov.y = sv.y * k; ov.z = sv.z * k; ov.w = sv.w * k;
    if (it < 2) {
      #pragma unroll
      for (int j = 0; j < 18; ++j) {
        float d = P[j].x * ov.x + P[j].y * ov.y + P[j].z * ov.z + P[j].w * ov.w;
        d += __shfl_xor(d, 16);
        d += __shfl_xor(d, 32);
        c[j] += __expf(d);
      }
    } else if (fq == 0) {
      // out[n][o*16 + l][h][w0+pix], l = q*4 + reg
      float* op = out + ((n * 8 + o) * 16 + (q << 2)) * 1024 + h * 32 + w0 + pix;
      op[0]    = ov.x;
      op[1024] = ov.y;
      op[2048] = ov.z;
      op[3072] = ov.w;
    }
  }
}

extern "C" void kernel_launch(void* const* d_in, const int* in_sizes, int n_in,
                              void* d_out, int out_size, void* d_ws, size_t ws_size,
                              hipStream_t stream) {
  const float* x = (const float*)d_in[0];
  const float* w = (const float*)d_in[1];
  float* outp    = (float*)d_out;
  ushort* wT = (ushort*)d_ws;                   // 9216 * 32 B = 294912 B
  ushort* xT = (ushort*)((char*)d_ws + 294912); // 4096 * 256 B = 1048576 B
  prep<<<dim3(68), dim3(256), 0, stream>>>(x, w, wT, xT);
  caps_main<<<dim3(2048), dim3(256), 0, stream>>>(wT, xT, outp);
}

// Round 4
// 77.434 us; speedup vs baseline: 1.4577x; 1.0093x over previous
//
#include <hip/hip_runtime.h>
#include <hip/hip_bf16.h>

// CapsuleConv2d fused, MFMA edition v3.
// N=4, C=64 (G=8 x IN_LEN=8), H=W=32, O=8, L=16, F=72 (G x 3x3), pad1 stride1.
//
// prep (1 kernel, 2 block ranges):
//   b<32  : x[n][c][h][w] fp32 -> xT per pixel: 64 uints [hi c0..63 | lo c0..63]
//           (bf16 split), via LDS transpose; coalesced reads AND writes.
//   b>=32 : w[o][f][l][p] fp32 -> wT records of 16 ushorts [hi p0..7 | lo p0..7].
// caps_main: block = (n,o,h,wtile16), 4 waves = 4 f-quadrants (18 f each).
//   Priors: one mfma_f32_16x16x32_bf16 per f; K-octets give the EXACT product:
//     q0: w_hi*x_hi, q1: w_hi*x_lo, q2: w_lo*x_hi, q3: w_lo*x_lo.
//   D-layout: col=lane&15=pix, row=(lane>>4)*4+reg=l  [m89-verified].
//   Routing in D-layout; cross-wave f-sum via double-buffered LDS (1 barrier/iter).
//   v3: ALL intra-wave reduces (delta over l-quads, squash qq) use gfx950
//   v_permlane16/32_swap_b32 (VALU pipe, ~4cy) instead of ds_swizzle/bpermute
//   (LDS pipe, ~120cy latency) -- removes ~78 LDS ops/wave and the lgkmcnt chains.

typedef short bf16x8 __attribute__((ext_vector_type(8)));
typedef float f32x4 __attribute__((ext_vector_type(4)));
typedef unsigned int uint2v __attribute__((ext_vector_type(2)));

__device__ __forceinline__ float red16(float v) {
#if __has_builtin(__builtin_amdgcn_permlane16_swap)
  uint2v r = __builtin_amdgcn_permlane16_swap(__float_as_uint(v), __float_as_uint(v),
                                              false, false);
  return __uint_as_float(r[0]) + __uint_as_float(r[1]);
#else
  return v + __shfl_xor(v, 16);
#endif
}

__device__ __forceinline__ float red32(float v) {
#if __has_builtin(__builtin_amdgcn_permlane32_swap)
  uint2v r = __builtin_amdgcn_permlane32_swap(__float_as_uint(v), __float_as_uint(v),
                                              false, false);
  return __uint_as_float(r[0]) + __uint_as_float(r[1]);
#else
  return v + __shfl_xor(v, 32);
#endif
}

__device__ __forceinline__ uint pack_split(float v) {
  __hip_bfloat16 hb = __float2bfloat16(v);
  float hf = __bfloat162float(hb);
  __hip_bfloat16 lb = __float2bfloat16(v - hf);
  return (uint)(*(ushort*)&hb) | ((uint)(*(ushort*)&lb) << 16);
}

__global__ __launch_bounds__(256)
void prep(const float* __restrict__ x, const float* __restrict__ w,
          ushort* __restrict__ wT, ushort* __restrict__ xT) {
  const int b = blockIdx.x;
  if (b < 32) {
    // ---- x part: n = b>>3, 4 h-rows starting h0 ----
    __shared__ uint lds[128 * 65];  // [pix 0..127][c 0..63], hi|lo packed
    const int n = b >> 3, h0 = (b & 7) * 4;
    const float* src = x + n * 65536 + h0 * 32;
    for (int i = threadIdx.x; i < 8192; i += 256) {
      const int c = i >> 7, p = i & 127;           // coalesced 128-float runs
      lds[p * 65 + c] = pack_split(src[c * 1024 + p]);
    }
    __syncthreads();
    uint* dst = (uint*)xT + (n * 1024 + h0 * 32) * 64;
    for (int i = threadIdx.x; i < 2048; i += 256) {
      const int pix = i >> 4, seg = i & 15;        // seg 0..7 -> hi, 8..15 -> lo
      const uint* row = &lds[pix * 65 + (seg & 7) * 8];
      uint4 v;
      if (seg < 8) {
        v.x = (row[0] & 0xffffu) | (row[1] << 16);
        v.y = (row[2] & 0xffffu) | (row[3] << 16);
        v.z = (row[4] & 0xffffu) | (row[5] << 16);
        v.w = (row[6] & 0xffffu) | (row[7] << 16);
      } else {
        v.x = (row[0] >> 16) | (row[1] & 0xffff0000u);
        v.y = (row[2] >> 16) | (row[3] & 0xffff0000u);
        v.z = (row[4] >> 16) | (row[5] & 0xffff0000u);
        v.w = (row[6] >> 16) | (row[7] & 0xffff0000u);
      }
      *(uint4*)(dst + pix * 64 + seg * 4) = v;     // fully coalesced 16B stores
    }
  } else {
    // ---- w part: t = record index (o*72+f)*16+l, 9216 total ----
    const int t = (b - 32) * 256 + threadIdx.x;
    if (t >= 9216) return;
    const float* src = w + t * 8;
    uint hi[4], lo[4];
    #pragma unroll
    for (int p2 = 0; p2 < 4; ++p2) {
      uint a = pack_split(src[p2 * 2]);
      uint c = pack_split(src[p2 * 2 + 1]);
      hi[p2] = (a & 0xffffu) | (c << 16);
      lo[p2] = (a >> 16) | (c & 0xffff0000u);
    }
    uint* dstp = (uint*)(wT + t * 16);
    *(uint4*)dstp       = make_uint4(hi[0], hi[1], hi[2], hi[3]);
    *(uint4*)(dstp + 4) = make_uint4(lo[0], lo[1], lo[2], lo[3]);
  }
}

__global__ __launch_bounds__(256, 3)
void caps_main(const ushort* __restrict__ wT, const ushort* __restrict__ xT,
               float* __restrict__ out) {
  const int b  = blockIdx.x;
  const int wt = b & 1, h = (b >> 1) & 31, o = (b >> 6) & 7, n = b >> 9;
  const int w0 = wt * 16;
  const int tid = threadIdx.x, lane = tid & 63, fq = tid >> 6;
  const int pix = lane & 15, q = lane >> 4;

  // x window: 3 rows x 18 cols, per col 64 uints ([hi 32 | lo 32]), stride 68
  __shared__ uint  xs[54 * 68];          // 14688 B
  __shared__ float sbuf[2][4 * 256];     // 8192 B, double-buffered s exchange

  // ---- stage x window (uint4 copies; zero-fill pads) ----
  for (int i = tid; i < 54 * 16; i += 256) {
    const int r = i >> 4, seg = i & 15;
    const int kh = r / 18, c = r % 18;
    const int hh = h + kh - 1, ww = w0 + c - 1;
    uint4 v = make_uint4(0u, 0u, 0u, 0u);
    if ((unsigned)hh < 32u && (unsigned)ww < 32u) {
      const uint* g = (const uint*)xT + (n * 1024 + hh * 32 + ww) * 64 + seg * 4;
      v = *(const uint4*)g;
    }
    *(uint4*)&xs[r * 68 + seg * 4] = v;
  }
  __syncthreads();

  // ---- priors: 18 MFMAs, one per f = fq*18 + j; exact bf16-split product ----
  f32x4 P[18];
  const f32x4 zacc = {0.f, 0.f, 0.f, 0.f};
  // A: lane m holds record (o, f, l=m); k-octet q reads hi (q<2) or lo (q>=2).
  const ushort* wA = wT + ((o * 72 + fq * 18) * 16 + pix) * 16 + ((q >= 2) ? 8 : 0);
  // B: k-octet q reads hi (q even) / lo (q odd) half of the x column.
  const int xw_lane = pix * 68 + ((q & 1) ? 32 : 0);
  #pragma unroll
  for (int j = 0; j < 18; ++j) {
    const int g = fq * 2 + (j >= 9 ? 1 : 0);
    const int s = j % 9, kh = s / 3, kw = s % 3;
    const bf16x8 a  = *(const bf16x8*)(wA + j * 256);
    const bf16x8 bv = *(const bf16x8*)&xs[(kh * 18 + kw) * 68 + g * 4 + xw_lane];
    P[j] = __builtin_amdgcn_mfma_f32_16x16x32_bf16(a, bv, zacc, 0, 0, 0);
  }

  // ---- routing: lane owns (pix, l = q*4 + reg), 18 f x 4 l priors in regs ----
  float c[18];
  #pragma unroll
  for (int j = 0; j < 18; ++j) c[j] = 1.f;

  const int sidx = pix * 16 + (q << 2);  // [pix][l] within a wave's 256-float tile
  #pragma unroll
  for (int it = 0; it < 3; ++it) {
    f32x4 sp = {0.f, 0.f, 0.f, 0.f};
    #pragma unroll
    for (int j = 0; j < 18; ++j) {
      sp.x += c[j] * P[j].x; sp.y += c[j] * P[j].y;
      sp.z += c[j] * P[j].z; sp.w += c[j] * P[j].w;
    }
    float* sb = sbuf[it & 1];
    *(f32x4*)&sb[fq * 256 + sidx] = sp;
    __syncthreads();
    f32x4 sv = *(const f32x4*)&sb[sidx];
    #pragma unroll
    for (int k4 = 1; k4 < 4; ++k4) {
      f32x4 t = *(const f32x4*)&sb[k4 * 256 + sidx];
      sv.x += t.x; sv.y += t.y; sv.z += t.z; sv.w += t.w;
    }
    sv.x *= 0.125f; sv.y *= 0.125f; sv.z *= 0.125f; sv.w *= 0.125f;
    // squash: qq = sum_l s^2  (4 in-reg + VALU permlane reduce over the 4 lq lanes)
    float qq = sv.x * sv.x + sv.y * sv.y + sv.z * sv.z + sv.w * sv.w;
    qq = red32(red16(qq));
    const float k = sqrtf(qq) / (1.f + qq);
    f32x4 ov;
    ov.x = sv.x * k; ov.y = sv.y * k; ov.z = sv.z * k; ov.w = sv.w * k;
    if (it < 2) {
      #pragma unroll
      for (int j = 0; j < 18; ++j) {
        float d = P[j].x * ov.x + P[j].y * ov.y + P[j].z * ov.z + P[j].w * ov.w;
        d = red32(red16(d));            // VALU permlane butterfly, no LDS
        c[j] += __expf(d);
      }
    } else if (fq == 0) {
      // out[n][o*16 + l][h][w0+pix], l = q*4 + reg
      float* op = out + ((n * 8 + o) * 16 + (q << 2)) * 1024 + h * 32 + w0 + pix;
      op[0]    = ov.x;
      op[1024] = ov.y;
      op[2048] = ov.z;
      op[3072] = ov.w;
    }
  }
}

extern "C" void kernel_launch(void* const* d_in, const int* in_sizes, int n_in,
                              void* d_out, int out_size, void* d_ws, size_t ws_size,
                              hipStream_t stream) {
  const float* x = (const float*)d_in[0];
  const float* w = (const float*)d_in[1];
  float* outp    = (float*)d_out;
  ushort* wT = (ushort*)d_ws;                   // 9216 * 32 B = 294912 B
  ushort* xT = (ushort*)((char*)d_ws + 294912); // 4096 * 256 B = 1048576 B
  prep<<<dim3(68), dim3(256), 0, stream>>>(x, w, wT, xT);
  caps_main<<<dim3(2048), dim3(256), 0, stream>>>(wT, xT, outp);
}